// Round 18
// baseline (50.697 us; speedup 1.0000x reference)
//
#include <hip/hip_runtime.h>
#include <hip/hip_bf16.h>
#include <string.h>

typedef __attribute__((ext_vector_type(8))) short bf16x8;
typedef __attribute__((ext_vector_type(4))) float f32x4;

namespace {
constexpr int B = 8, H = 128, W = 128, C = 128;
constexpr int MO = 9, NOFF = 81;
constexpr int ROWS = 4;            // output rows per block (1 per wave)
constexpr int WCOLS = 16;          // output cols per block
constexpr int F2R = 12;            // staged F2 rows (4 + 2*4 halo)
constexpr int SREAL = 24;          // staged cols, fx = wb0-4 .. wb0+19
constexpr int NT = 256;            // 4 waves
constexpr int NLD = 9;             // float4 loads per thread per k-slab
constexpr int KSTR = SREAL * 32;   // 768 shorts per k-slab (32 ch)
constexpr int ROWSTR = 4 * KSTR;   // 3072 shorts per staged row (128 ch)
constexpr int PADS = 256;          // tail pad: b1 spill of (ry=11,kk=3) lands here
}

__device__ inline unsigned bf2pack(float a, float b) {
  // RTNE fp32->bf16 pair via v_cvt_pk_bf16_f32 (a = low half)
  __hip_bfloat162 h = __float22bfloat162_rn(float2{a, b});
  unsigned r;
  memcpy(&r, &h, sizeof(r));
  return r;
}

__device__ __forceinline__ f32x4 mfma16(bf16x8 a, bf16x8 b, f32x4 c) {
  return __builtin_amdgcn_mfma_f32_16x16x32_bf16(a, b, c, 0, 0, 0);
}

__global__ __launch_bounds__(NT, 2) void costvol_kernel(
    const float* __restrict__ F1, const float* __restrict__ F2,
    float* __restrict__ out)
{
  // Single buffer, whole 128-ch tile: [ry][kk][s][32ch] bf16 = 74,240 B.
  __shared__ __align__(16) short sF2[F2R * ROWSTR + PADS];

  const int lin  = blockIdx.x;
  // convoy breaker (r15, kept): anti-phase initially-resident pairs.
  if (lin < 512 && ((lin ^ (lin >> 8)) & 1)) {
    __builtin_amdgcn_s_sleep(101);
  }

  const int b    = lin & 7;          // one batch per XCD
  const int tile = lin >> 3;         // 0..255
  const int rt   = tile & 31;        // rt fastest: halo rows reuse in L2
  const int wt   = tile >> 5;        // 0..7
  const int h0   = rt * ROWS;
  const int wb0  = wt * WCOLS;

  const int tid  = threadIdx.x;
  const int r    = tid >> 6;         // wave index = output row in tile
  const int lane = tid & 63;
  const int j    = lane & 15;        // MFMA m/n index
  const int kq   = lane >> 4;        // k-quarter within a slab

  // ---- loop-invariant staging decode (OOB -> offset 0, skipped at pack)
  int gofs[NLD]; int lofs[NLD]; unsigned okm = 0;
#pragma unroll
  for (int it = 0; it < NLD; ++it) {
    const int idx  = tid + it * NT;   // 0..2303
    const int kg   = idx & 7;         // channel-quad within slab
    const int slot = idx >> 3;        // 0..287 -> (ry, s)
    const int ry   = slot / SREAL;
    const int s    = slot - ry * SREAL;
    const int fy   = h0 - 4 + ry;
    const int fx   = wb0 - 4 + s;
    const bool ok  = ((unsigned)fy < 128u) && ((unsigned)fx < 128u);
    okm |= (unsigned)ok << it;
    gofs[it] = ok ? (((b * H + fy) * W + fx) * C + kg * 4) : 0;
    lofs[it] = ry * ROWSTR + s * 32 + kg * 4;
  }

  auto issue = [&](int g, float4* ld) {
#pragma unroll
    for (int it = 0; it < NLD; ++it) {
      ld[it] = *reinterpret_cast<const float4*>(F2 + gofs[it] + g * 32);
    }
    __builtin_amdgcn_sched_barrier(0);  // loads must issue here, not sink
  };
  auto pack = [&](int g, const float4* ld) {
#pragma unroll
    for (int it = 0; it < NLD; ++it) {
      if ((okm >> it) & 1u) {
        uint2 p;
        p.x = bf2pack(ld[it].x, ld[it].y);
        p.y = bf2pack(ld[it].z, ld[it].w);
        *reinterpret_cast<uint2*>(&sF2[lofs[it] + g * KSTR]) = p;
      }
    }
  };

  // ---- rolling staging pipeline: 2 groups in flight, 4 slabs total
  float4 ldA[NLD], ldB[NLD];
  issue(0, ldA);
  issue(1, ldB);
  // zero OOB slots (all 4 slabs) while g0 is in flight
#pragma unroll
  for (int it = 0; it < NLD; ++it) {
    if (!((okm >> it) & 1u)) {
#pragma unroll
      for (int g = 0; g < 4; ++g) {
        *reinterpret_cast<uint2*>(&sF2[lofs[it] + g * KSTR]) = uint2{0u, 0u};
      }
    }
  }
  pack(0, ldA);
  issue(2, ldA);
  pack(1, ldB);
  issue(3, ldB);
  pack(2, ldA);

  // F1 fragments direct from global (consumed after pack(3))
  const float* f1p = F1 + (((size_t)b * H + h0 + r) * W + wb0 + j) * C + kq * 8;
  float4 u0[4], u1[4];
#pragma unroll
  for (int kk = 0; kk < 4; ++kk) {
    u0[kk] = *reinterpret_cast<const float4*>(f1p + kk * 32);
    u1[kk] = *reinterpret_cast<const float4*>(f1p + kk * 32 + 4);
  }
  __builtin_amdgcn_sched_barrier(0);
  pack(3, ldB);

  // afrag with 1/128 prescale (exact exponent shift; epilogue mul removed)
  bf16x8 afrag[4];
  constexpr float S = 0.0078125f;
#pragma unroll
  for (int kk = 0; kk < 4; ++kk) {
    uint4 q;
    q.x = bf2pack(u0[kk].x * S, u0[kk].y * S);
    q.y = bf2pack(u0[kk].z * S, u0[kk].w * S);
    q.z = bf2pack(u1[kk].x * S, u1[kk].y * S);
    q.w = bf2pack(u1[kk].z * S, u1[kk].w * S);
    afrag[kk] = __builtin_bit_cast(bf16x8, q);
  }

  __syncthreads();  // the ONLY barrier

  // ---- compute burst: 72 ds_read_b128 + 72 MFMA
  f32x4 acc[9][2];
#pragma unroll
  for (int d = 0; d < 9; ++d) { acc[d][0] = {0,0,0,0}; acc[d][1] = {0,0,0,0}; }

  const short* bb = sF2 + j * 32 + kq * 8;
  __builtin_amdgcn_s_setprio(1);
#pragma unroll
  for (int kk = 0; kk < 4; ++kk) {
    const short* bk = bb + kk * KSTR;
#pragma unroll
    for (int dy = 0; dy < 9; ++dy) {
      const short* brow = bk + (r + dy) * ROWSTR;
      const bf16x8 b0 = *reinterpret_cast<const bf16x8*>(brow);
      const bf16x8 b1 = *reinterpret_cast<const bf16x8*>(brow + 512);
      acc[dy][0] = mfma16(afrag[kk], b0, acc[dy][0]);
      acc[dy][1] = mfma16(afrag[kk], b1, acc[dy][1]);
    }
  }
  __builtin_amdgcn_s_setprio(0);

  // ---- epilogue: band extract, leaky_relu(0.1), NONTEMPORAL store.
  // nt stores keep the 42MB/replay output stream from evicting the
  // L3-resident inputs (the round-18 single-variable change).
  // out idx = i*81 + dy*9 + dxi, i = kq*4+reg, dxi = j+16t-i
  float* lb = out + (((size_t)b * H + h0 + r) * W + wb0) * NOFF + kq * 320 + j;
#pragma unroll
  for (int t = 0; t < 2; ++t) {
#pragma unroll
    for (int reg = 0; reg < 4; ++reg) {
      const int dxl = j + 16 * t - kq * 4 - reg;  // lane-dependent dxi
      if ((unsigned)dxl <= 8u) {
#pragma unroll
        for (int dy = 0; dy < 9; ++dy) {
          float m = acc[dy][t][reg];               // already /128 via prescale
          m = fmaxf(m, 0.1f * m);                  // leaky_relu(0.1)
          __builtin_nontemporal_store(m, &lb[reg * 80 + 16 * t + dy * 9]);
        }
      }
    }
  }
}

extern "C" void kernel_launch(void* const* d_in, const int* in_sizes, int n_in,
                              void* d_out, int out_size, void* d_ws, size_t ws_size,
                              hipStream_t stream) {
  const float* F1 = (const float*)d_in[0];
  const float* F2 = (const float*)d_in[1];
  float* out = (float*)d_out;
  dim3 grid(B * (H / ROWS) * (W / WCOLS));  // 8 * 32 * 8 = 2048 blocks
  dim3 block(NT);                           // 256 threads = 4 waves
  hipLaunchKernelGGL(costvol_kernel, grid, block, 0, stream, F1, F2, out);
}

// Round 19
// 42.920 us; speedup vs baseline: 1.1812x; 1.1812x over previous
//
#include <hip/hip_runtime.h>
#include <hip/hip_bf16.h>
#include <string.h>

typedef __attribute__((ext_vector_type(8))) short bf16x8;
typedef __attribute__((ext_vector_type(4))) float f32x4;

namespace {
constexpr int B = 8, H = 128, W = 128, C = 128;
constexpr int MO = 9, NOFF = 81;
constexpr int ROWS = 4;            // output rows per block (1 per wave)
constexpr int WCOLS = 16;          // output cols per block
constexpr int F2R = 12;            // staged F2 rows (4 + 2*4 halo)
constexpr int SREAL = 24;          // staged cols, fx = wb0-4 .. wb0+19
constexpr int NT = 256;            // 4 waves
constexpr int NLD = 9;             // float4 loads per thread per k-slab
constexpr int KSTR = SREAL * 32;   // 768 shorts per k-slab (32 ch)
constexpr int ROWSTR = 4 * KSTR;   // 3072 shorts per staged row (128 ch)
constexpr int PADS = 256;          // tail pad: b1 spill of (ry=11,kk=3) lands here
}

__device__ inline unsigned bf2pack(float a, float b) {
  // RTNE fp32->bf16 pair via v_cvt_pk_bf16_f32 (a = low half)
  __hip_bfloat162 h = __float22bfloat162_rn(float2{a, b});
  unsigned r;
  memcpy(&r, &h, sizeof(r));
  return r;
}

__device__ __forceinline__ f32x4 mfma16(bf16x8 a, bf16x8 b, f32x4 c) {
  return __builtin_amdgcn_mfma_f32_16x16x32_bf16(a, b, c, 0, 0, 0);
}

__global__ __launch_bounds__(NT, 2) void costvol_kernel(
    const float* __restrict__ F1, const float* __restrict__ F2,
    float* __restrict__ out)
{
  // Single buffer, whole 128-ch tile: [ry][kk][s][32ch] bf16 = 74,240 B.
  __shared__ __align__(16) short sF2[F2R * ROWSTR + PADS];

  const int lin  = blockIdx.x;
  // convoy breaker (r15, kept): anti-phase initially-resident pairs.
  if (lin < 512 && ((lin ^ (lin >> 8)) & 1)) {
    __builtin_amdgcn_s_sleep(101);
  }

  const int b    = lin & 7;          // one batch per XCD
  const int tile = lin >> 3;         // 0..255
  // r19 change: wt-FASTEST. Concurrent blocks on an XCD share the same
  // 12-row full-width band (786KB, L2-hot) and their col-halos overlap in
  // time -> F2 col-halo reads become L2 hits instead of HBM re-fetch.
  const int wt   = tile & 7;         // 0..7 (fastest)
  const int rt   = tile >> 3;        // 0..31
  const int h0   = rt * ROWS;
  const int wb0  = wt * WCOLS;

  const int tid  = threadIdx.x;
  const int r    = tid >> 6;         // wave index = output row in tile
  const int lane = tid & 63;
  const int j    = lane & 15;        // MFMA m/n index
  const int kq   = lane >> 4;        // k-quarter within a slab

  // ---- loop-invariant staging decode (OOB -> offset 0, skipped at pack)
  int gofs[NLD]; int lofs[NLD]; unsigned okm = 0;
#pragma unroll
  for (int it = 0; it < NLD; ++it) {
    const int idx  = tid + it * NT;   // 0..2303
    const int kg   = idx & 7;         // channel-quad within slab
    const int slot = idx >> 3;        // 0..287 -> (ry, s)
    const int ry   = slot / SREAL;
    const int s    = slot - ry * SREAL;
    const int fy   = h0 - 4 + ry;
    const int fx   = wb0 - 4 + s;
    const bool ok  = ((unsigned)fy < 128u) && ((unsigned)fx < 128u);
    okm |= (unsigned)ok << it;
    gofs[it] = ok ? (((b * H + fy) * W + fx) * C + kg * 4) : 0;
    lofs[it] = ry * ROWSTR + s * 32 + kg * 4;
  }

  auto issue = [&](int g, float4* ld) {
#pragma unroll
    for (int it = 0; it < NLD; ++it) {
      ld[it] = *reinterpret_cast<const float4*>(F2 + gofs[it] + g * 32);
    }
    __builtin_amdgcn_sched_barrier(0);  // loads must issue here, not sink
  };
  auto pack = [&](int g, const float4* ld) {
#pragma unroll
    for (int it = 0; it < NLD; ++it) {
      if ((okm >> it) & 1u) {
        uint2 p;
        p.x = bf2pack(ld[it].x, ld[it].y);
        p.y = bf2pack(ld[it].z, ld[it].w);
        *reinterpret_cast<uint2*>(&sF2[lofs[it] + g * KSTR]) = p;
      }
    }
  };

  // ---- rolling staging pipeline: 2 groups in flight, 4 slabs total
  float4 ldA[NLD], ldB[NLD];
  issue(0, ldA);
  issue(1, ldB);
  // zero OOB slots (all 4 slabs) while g0 is in flight
#pragma unroll
  for (int it = 0; it < NLD; ++it) {
    if (!((okm >> it) & 1u)) {
#pragma unroll
      for (int g = 0; g < 4; ++g) {
        *reinterpret_cast<uint2*>(&sF2[lofs[it] + g * KSTR]) = uint2{0u, 0u};
      }
    }
  }
  pack(0, ldA);
  issue(2, ldA);
  pack(1, ldB);
  issue(3, ldB);
  pack(2, ldA);

  // F1 fragments direct from global (consumed after pack(3))
  const float* f1p = F1 + (((size_t)b * H + h0 + r) * W + wb0 + j) * C + kq * 8;
  float4 u0[4], u1[4];
#pragma unroll
  for (int kk = 0; kk < 4; ++kk) {
    u0[kk] = *reinterpret_cast<const float4*>(f1p + kk * 32);
    u1[kk] = *reinterpret_cast<const float4*>(f1p + kk * 32 + 4);
  }
  __builtin_amdgcn_sched_barrier(0);
  pack(3, ldB);

  // afrag with 1/128 prescale (exact exponent shift; epilogue mul removed)
  bf16x8 afrag[4];
  constexpr float S = 0.0078125f;
#pragma unroll
  for (int kk = 0; kk < 4; ++kk) {
    uint4 q;
    q.x = bf2pack(u0[kk].x * S, u0[kk].y * S);
    q.y = bf2pack(u0[kk].z * S, u0[kk].w * S);
    q.z = bf2pack(u1[kk].x * S, u1[kk].y * S);
    q.w = bf2pack(u1[kk].z * S, u1[kk].w * S);
    afrag[kk] = __builtin_bit_cast(bf16x8, q);
  }

  __syncthreads();  // the ONLY barrier

  // ---- compute burst: 72 ds_read_b128 + 72 MFMA
  f32x4 acc[9][2];
#pragma unroll
  for (int d = 0; d < 9; ++d) { acc[d][0] = {0,0,0,0}; acc[d][1] = {0,0,0,0}; }

  const short* bb = sF2 + j * 32 + kq * 8;
  __builtin_amdgcn_s_setprio(1);
#pragma unroll
  for (int kk = 0; kk < 4; ++kk) {
    const short* bk = bb + kk * KSTR;
#pragma unroll
    for (int dy = 0; dy < 9; ++dy) {
      const short* brow = bk + (r + dy) * ROWSTR;
      const bf16x8 b0 = *reinterpret_cast<const bf16x8*>(brow);
      const bf16x8 b1 = *reinterpret_cast<const bf16x8*>(brow + 512);
      acc[dy][0] = mfma16(afrag[kk], b0, acc[dy][0]);
      acc[dy][1] = mfma16(afrag[kk], b1, acc[dy][1]);
    }
  }
  __builtin_amdgcn_s_setprio(0);

  // ---- epilogue: band extract, leaky_relu(0.1), store
  // out idx = i*81 + dy*9 + dxi, i = kq*4+reg, dxi = j+16t-i
  float* lb = out + (((size_t)b * H + h0 + r) * W + wb0) * NOFF + kq * 320 + j;
#pragma unroll
  for (int t = 0; t < 2; ++t) {
#pragma unroll
    for (int reg = 0; reg < 4; ++reg) {
      const int dxl = j + 16 * t - kq * 4 - reg;  // lane-dependent dxi
      if ((unsigned)dxl <= 8u) {
#pragma unroll
        for (int dy = 0; dy < 9; ++dy) {
          float m = acc[dy][t][reg];               // already /128 via prescale
          m = fmaxf(m, 0.1f * m);                  // leaky_relu(0.1)
          lb[reg * 80 + 16 * t + dy * 9] = m;      // const offset folds to imm
        }
      }
    }
  }
}

extern "C" void kernel_launch(void* const* d_in, const int* in_sizes, int n_in,
                              void* d_out, int out_size, void* d_ws, size_t ws_size,
                              hipStream_t stream) {
  const float* F1 = (const float*)d_in[0];
  const float* F2 = (const float*)d_in[1];
  float* out = (float*)d_out;
  dim3 grid(B * (H / ROWS) * (W / WCOLS));  // 8 * 32 * 8 = 2048 blocks
  dim3 block(NT);                           // 256 threads = 4 waves
  hipLaunchKernelGGL(costvol_kernel, grid, block, 0, stream, F1, F2, out);
}